// Round 1
// baseline (507.790 us; speedup 1.0000x reference)
//
#include <hip/hip_runtime.h>
#include <hip/hip_bf16.h>
#include <stdint.h>

// Problem constants (fixed shapes)
#define BB 16
#define HH 32
#define WW 64
#define CC 768
#define W2C 33                   // WW/2+1
#define MSPEC (BB*HH*W2C)        // 16896 frequency points
#define ROWW (2*CC)              // 1536 = NB*2*BS, spectral row layout (nb, re/im, bs)

typedef __bf16 bf16x8 __attribute__((ext_vector_type(8)));
typedef float f32x4 __attribute__((ext_vector_type(4)));

__device__ __forceinline__ unsigned short f2bf(float f) {
  __hip_bfloat16 h = __float2bfloat16(f);
  return __builtin_bit_cast(unsigned short, h);
}
__device__ __forceinline__ float bf2f(unsigned short u) {
  union { unsigned int i; float f; } x;
  x.i = ((unsigned int)u) << 16;
  return x.f;
}

// async global->LDS, 16B per lane (guide Sec 5: the m93->m97 2x step)
__device__ __forceinline__ void g2l16(const void* g, void* l) {
  __builtin_amdgcn_global_load_lds((const __attribute__((address_space(1))) unsigned int*)g,
                                   (__attribute__((address_space(3))) unsigned int*)l,
                                   16, 0, 0);
}

// compile-time bit reversal (folds after full unroll -> keeps v[] in VGPRs)
__device__ __host__ constexpr int brevc(int x, int bits) {
  int r = 0;
  for (int i = 0; i < bits; ++i) r |= ((x >> i) & 1) << (bits - 1 - i);
  return r;
}

// ---------------- radix-2 DIF FFT in registers ----------------
// tw[x] = (cos(2pi x/64), -sin(2pi x/64))  (forward twiddles, 64-base table)
// After the stages, X[k] = v[bitrev(k)].
template<int N, bool INV>
__device__ __forceinline__ void fft_reg(float2 (&v)[N], const float2* __restrict__ tw) {
  constexpr int LOG2N = (N == 64) ? 6 : 5;
#pragma unroll
  for (int s = 0; s < LOG2N; ++s) {
    const int len = N >> s;
    const int half = len >> 1;
    const int tstep = 64 / len;
#pragma unroll
    for (int i = 0; i < N; i += len) {
#pragma unroll
      for (int j = 0; j < half; ++j) {
        float2 u = v[i + j];
        float2 t = v[i + j + half];
        float sr = u.x + t.x, si = u.y + t.y;
        float dr = u.x - t.x, di = u.y - t.y;
        float2 w = tw[j * tstep];
        float wr = w.x;
        float wi = INV ? -w.y : w.y;
        v[i + j] = make_float2(sr, si);
        v[i + j + half] = make_float2(dr * wr - di * wi, dr * wi + di * wr);
      }
    }
  }
}

#define TW_INIT()                                                            \
  __shared__ float2 tw[64];                                                  \
  if (threadIdx.x < 64) {                                                    \
    float ang = (float)threadIdx.x * 0.09817477042468103f; /* 2pi/64 */      \
    tw[threadIdx.x] = make_float2(cosf(ang), -sinf(ang));                    \
  }                                                                          \
  __syncthreads();

// ---------------- forward FFT pass A: real DFT along W (64 -> 33 cplx) ----------------
// grid (BB*HH, 3), block 256. thread: one (b,h,c) line.
__global__ __launch_bounds__(256) void fft_fwd_w(const float* __restrict__ x,
                                                 ushort2* __restrict__ yw) {
  TW_INIT();
  const int bh = blockIdx.x;
  const int c = blockIdx.y * 256 + threadIdx.x;
  const float* xp = x + (size_t)bh * (WW * CC) + c;
  float2 v[64];
#pragma unroll
  for (int w = 0; w < 64; ++w) v[w] = make_float2(xp[(size_t)w * CC], 0.f);
  fft_reg<64, false>(v, tw);
  ushort2* yp = yw + (size_t)bh * (W2C * CC) + c;
#pragma unroll
  for (int k = 0; k <= 32; ++k) {
    float2 z = v[brevc(k, 6)];
    yp[(size_t)k * CC] = make_ushort2(f2bf(z.x), f2bf(z.y));
  }
}

// ---------------- forward FFT pass B: complex DFT along H (32), scale, write GEMM layout ---
// grid (BB*W2C, 3). Output Xf: (m, nb, re/im, bs) bf16, m = (b*32+kh)*33+kw
__global__ __launch_bounds__(256) void fft_fwd_h(const ushort2* __restrict__ yw,
                                                 unsigned short* __restrict__ xf) {
  TW_INIT();
  const int bk = blockIdx.x;
  const int b = bk / W2C, kw = bk - b * W2C;
  const int c = blockIdx.y * 256 + threadIdx.x;
  const ushort2* yp = yw + ((size_t)b * HH * W2C + kw) * CC + c;
  float2 v[32];
#pragma unroll
  for (int h = 0; h < 32; ++h) {
    ushort2 u = yp[(size_t)h * (W2C * CC)];
    v[h] = make_float2(bf2f(u.x), bf2f(u.y));
  }
  fft_reg<32, false>(v, tw);
  const int nb = c / 192, cc = c - nb * 192;
  unsigned short* xp = xf + (size_t)nb * 384 + cc;
  const float s = 0.022097086912079608f; // 1/sqrt(2048)  (ortho fwd)
#pragma unroll
  for (int kh = 0; kh < 32; ++kh) {
    float2 z = v[brevc(kh, 5)];
    size_t m = ((size_t)b * HH + kh) * W2C + kw;
    xp[m * ROWW] = f2bf(z.x * s);
    xp[m * ROWW + 192] = f2bf(z.y * s);
  }
}

// ---------------- inverse FFT pass A: complex inverse DFT along H ----------------
__global__ __launch_bounds__(256) void fft_inv_h(const unsigned short* __restrict__ r2,
                                                 ushort2* __restrict__ g) {
  TW_INIT();
  const int bk = blockIdx.x;
  const int b = bk / W2C, kw = bk - b * W2C;
  const int c = blockIdx.y * 256 + threadIdx.x;
  const int nb = c / 192, cc = c - nb * 192;
  const unsigned short* rp = r2 + (size_t)nb * 384 + cc;
  float2 v[32];
#pragma unroll
  for (int kh = 0; kh < 32; ++kh) {
    size_t m = ((size_t)b * HH + kh) * W2C + kw;
    v[kh] = make_float2(bf2f(rp[m * ROWW]), bf2f(rp[m * ROWW + 192]));
  }
  fft_reg<32, true>(v, tw);
  ushort2* gp = g + ((size_t)b * HH * W2C + kw) * CC + c;
#pragma unroll
  for (int h = 0; h < 32; ++h) {
    float2 z = v[brevc(h, 5)];
    gp[(size_t)h * (W2C * CC)] = make_ushort2(f2bf(z.x), f2bf(z.y));
  }
}

// ---------------- inverse FFT pass B: irfft along W (33 -> 64 real), add into out --------
// pocketfft c2r semantics: imag of bins 0 and 32 ignored. out already holds bias path.
__global__ __launch_bounds__(256) void fft_inv_w(const ushort2* __restrict__ g,
                                                 float* __restrict__ out) {
  TW_INIT();
  const int bh = blockIdx.x;
  const int c = blockIdx.y * 256 + threadIdx.x;
  const ushort2* gp = g + (size_t)bh * (W2C * CC) + c;
  float2 v[64];
  {
    ushort2 u0 = gp[0];
    v[0] = make_float2(bf2f(u0.x), 0.f);
    ushort2 u32 = gp[(size_t)32 * CC];
    v[32] = make_float2(bf2f(u32.x), 0.f);
  }
#pragma unroll
  for (int k = 1; k < 32; ++k) {
    ushort2 u = gp[(size_t)k * CC];
    float2 z = make_float2(bf2f(u.x), bf2f(u.y));
    v[k] = z;
    v[64 - k] = make_float2(z.x, -z.y); // hermitian extension
  }
  fft_reg<64, true>(v, tw);
  float* op = out + (size_t)bh * (WW * CC) + c;
  const float s = 0.022097086912079608f; // 1/sqrt(2048)  (ortho inv)
#pragma unroll
  for (int w = 0; w < 64; ++w) {
    float2 z = v[brevc(w, 6)];
    op[(size_t)w * CC] = op[(size_t)w * CC] + z.x * s;
  }
}

// ---------------- bf16 MFMA GEMM (m97 structure): out = A * B^T + bias ----------------
// A: (M x K) bf16 row-major, row stride lda, + z*aZ column offset
// Bw: B^T, n-major (N x K) bf16, + z*bZ elements
// exact tiles only: M%128==0, (N per z)%128==0, K%32==0
template<bool RELU, bool OBF>
__global__ __launch_bounds__(256) void gemm_bt(
    const unsigned short* __restrict__ A, int lda, int aZ,
    const unsigned short* __restrict__ Bw, int K, int bZ,
    const float* __restrict__ bias, int biasZ,
    void* __restrict__ outp, int ldo, int oZ) {
  __shared__ __align__(16) unsigned short As[128 * 32];
  __shared__ __align__(16) unsigned short Bs[128 * 32];
  const int t = threadIdx.x;
  const int z = blockIdx.z;
  const size_t m0 = (size_t)blockIdx.x * 128;
  const int n0 = blockIdx.y * 128;
  const unsigned short* Ap = A + m0 * lda + (size_t)z * aZ;
  const unsigned short* Bp = Bw + (size_t)n0 * K + (size_t)z * bZ;
  const int lane = t & 63, wave = t >> 6;
  const int lr = lane & 15, quad = lane >> 4;
  const int wm = (wave >> 1) * 64, wn = (wave & 1) * 64;
  const int row = t >> 2;        // 0..63
  const int kb = (t & 3) * 8;    // k element offset within 32-chunk
  f32x4 acc[4][4] = {};
  for (int k0 = 0; k0 < K; k0 += 32) {
    const unsigned short* ga = Ap + (size_t)row * lda + (k0 + kb);
    g2l16(ga, &As[row * 32 + kb]);
    g2l16(ga + (size_t)64 * lda, &As[(row + 64) * 32 + kb]);
    const unsigned short* gb = Bp + (size_t)row * K + (k0 + kb);
    g2l16(gb, &Bs[row * 32 + kb]);
    g2l16(gb + (size_t)64 * K, &Bs[(row + 64) * 32 + kb]);
    __syncthreads(); // compiler emits vmcnt(0) drain for global_load_lds
    bf16x8 af[4], bfr[4];
#pragma unroll
    for (int mi = 0; mi < 4; ++mi)
      af[mi] = *(const bf16x8*)&As[(wm + mi * 16 + lr) * 32 + quad * 8];
#pragma unroll
    for (int ni = 0; ni < 4; ++ni)
      bfr[ni] = *(const bf16x8*)&Bs[(wn + ni * 16 + lr) * 32 + quad * 8];
#pragma unroll
    for (int mi = 0; mi < 4; ++mi)
#pragma unroll
      for (int ni = 0; ni < 4; ++ni)
        acc[mi][ni] = __builtin_amdgcn_mfma_f32_16x16x32_bf16(af[mi], bfr[ni], acc[mi][ni], 0, 0, 0);
    __syncthreads();
  }
#pragma unroll
  for (int mi = 0; mi < 4; ++mi) {
    const size_t mrow = m0 + wm + mi * 16 + quad * 4;
#pragma unroll
    for (int ni = 0; ni < 4; ++ni) {
      const int ncol = n0 + wn + ni * 16 + lr;
      const float bv = bias[z * biasZ + ncol];
#pragma unroll
      for (int r = 0; r < 4; ++r) {
        float vv = acc[mi][ni][r] + bv;
        if (RELU) vv = fmaxf(vv, 0.f);
        const size_t off = (mrow + r) * (size_t)ldo + (size_t)z * oZ + ncol;
        if (OBF) ((unsigned short*)outp)[off] = f2bf(vv);
        else ((float*)outp)[off] = vv;
      }
    }
  }
}

// ---------------- prep kernels ----------------
__global__ __launch_bounds__(256) void cvt_bf16(const float* __restrict__ in,
                                                unsigned short* __restrict__ outp) {
  const size_t i = ((size_t)blockIdx.x * 256 + threadIdx.x) * 4;
  float4 v = *(const float4*)(in + i);
  ushort4 o = make_ushort4(f2bf(v.x), f2bf(v.y), f2bf(v.z), f2bf(v.w));
  *(ushort4*)(outp + i) = o;
}

// Combined layer-1 weights, stored n-major (nb, n, k), k,n in [0,384)
// [r1|i1] = relu([xr|xi] * [[W1r, W1i], [-W1i, W1r]] + [b1r|b1i])
__global__ __launch_bounds__(256) void build_w1(const float* __restrict__ w1,
                                                const float* __restrict__ b1,
                                                unsigned short* __restrict__ w1t,
                                                float* __restrict__ bias1) {
  const int idx = blockIdx.x * 256 + threadIdx.x;
  const int nb = idx / (384 * 384);
  const int rem = idx - nb * (384 * 384);
  const int n = rem / 384, k = rem - (rem / 384) * 384;
  const bool khi = k >= 192, nhi = n >= 192;
  const int kk = khi ? k - 192 : k, nn = nhi ? n - 192 : n;
  float val;
  if (!khi && !nhi)      val =  w1[((0 * 4 + nb) * 192 + kk) * 192 + nn];
  else if (khi && !nhi)  val = -w1[((1 * 4 + nb) * 192 + kk) * 192 + nn];
  else if (!khi && nhi)  val =  w1[((1 * 4 + nb) * 192 + kk) * 192 + nn];
  else                   val =  w1[((0 * 4 + nb) * 192 + kk) * 192 + nn];
  w1t[((size_t)nb * 384 + n) * 384 + k] = f2bf(val);
  if (k == 0)
    bias1[nb * 384 + n] = nhi ? b1[(1 * 4 + nb) * 192 + nn] : b1[(0 * 4 + nb) * 192 + nn];
}

// Combined layer-2 weights. i2 = r2*W2i + i1*W2r + b2i with r2 = r1*W2r - i1*W2i + b2r
//  => [r2|i2] = [r1|i1] * [[W2r, W2r*W2i], [-W2i, W2r - W2i*W2i]] + [b2r | b2r*W2i + b2i]
__global__ __launch_bounds__(256) void build_w2(const float* __restrict__ w2,
                                                const float* __restrict__ b2,
                                                unsigned short* __restrict__ w2t,
                                                float* __restrict__ bias2) {
  const int idx = blockIdx.x * 256 + threadIdx.x;
  const int nb = idx / (384 * 384);
  const int rem = idx - nb * (384 * 384);
  const int n = rem / 384, k = rem - (rem / 384) * 384;
  const bool khi = k >= 192, nhi = n >= 192;
  const int kk = khi ? k - 192 : k, nn = nhi ? n - 192 : n;
  float val;
  if (!khi && !nhi) {
    val = w2[((0 * 4 + nb) * 192 + kk) * 192 + nn];
  } else if (khi && !nhi) {
    val = -w2[((1 * 4 + nb) * 192 + kk) * 192 + nn];
  } else if (!khi && nhi) {
    float s = 0.f;
    for (int d = 0; d < 192; ++d)
      s += w2[((0 * 4 + nb) * 192 + kk) * 192 + d] * w2[((1 * 4 + nb) * 192 + d) * 192 + nn];
    val = s;
  } else {
    float s = 0.f;
    for (int d = 0; d < 192; ++d)
      s += w2[((1 * 4 + nb) * 192 + kk) * 192 + d] * w2[((1 * 4 + nb) * 192 + d) * 192 + nn];
    val = w2[((0 * 4 + nb) * 192 + kk) * 192 + nn] - s;
  }
  w2t[((size_t)nb * 384 + n) * 384 + k] = f2bf(val);
  if (k == 0) {
    float bv;
    if (!nhi) {
      bv = b2[(0 * 4 + nb) * 192 + nn];
    } else {
      float s = 0.f;
      for (int d = 0; d < 192; ++d)
        s += b2[(0 * 4 + nb) * 192 + d] * w2[((1 * 4 + nb) * 192 + d) * 192 + nn];
      bv = b2[(1 * 4 + nb) * 192 + nn] + s;
    }
    bias2[nb * 384 + n] = bv;
  }
}

// ---------------- launcher ----------------
extern "C" void kernel_launch(void* const* d_in, const int* in_sizes, int n_in,
                              void* d_out, int out_size, void* d_ws, size_t ws_size,
                              hipStream_t stream) {
  (void)in_sizes; (void)n_in; (void)out_size; (void)ws_size;
  const float* x  = (const float*)d_in[0];
  const float* w1 = (const float*)d_in[1];
  const float* b1 = (const float*)d_in[2];
  const float* w2 = (const float*)d_in[3];
  const float* b2 = (const float*)d_in[4];
  const float* bw = (const float*)d_in[5];
  const float* bb = (const float*)d_in[6];
  float* out = (float*)d_out;

  // workspace layout (aliased across lifetimes):
  //   buf1: Yw (fwd) -> R1I1 (L1 out) -> G (inv)      51,904,512 B
  //   buf2: x_bf16 -> R2I2 (L2 out)                   51,904,512 B
  //   xf  : spectral GEMM input                        51,904,512 B
  char* p = (char*)d_ws;
  unsigned short* buf1 = (unsigned short*)p; p += 51904512;
  unsigned short* buf2 = (unsigned short*)p; p += 51904512;
  unsigned short* xf   = (unsigned short*)p; p += 51904512;
  unsigned short* bwb  = (unsigned short*)p; p += 1179648;
  unsigned short* w1t  = (unsigned short*)p; p += 1179648;
  unsigned short* w2t  = (unsigned short*)p; p += 1179648;
  float* bias1 = (float*)p; p += 6144;
  float* bias2 = (float*)p; p += 6144;

  // 1) bf16 conversions
  cvt_bf16<<<25165824 / 1024, 256, 0, stream>>>(x, buf2);
  cvt_bf16<<<589824 / 1024, 256, 0, stream>>>(bw, bwb);
  // 2) bias path GEMM: out = x @ bias_w^T + bias_b   (M=32768, N=768, K=768)
  gemm_bt<false, false><<<dim3(256, 6, 1), 256, 0, stream>>>(
      buf2, 768, 0, bwb, 768, 0, bb, 0, out, 768, 0);
  // 3) combined spectral weights
  build_w1<<<589824 / 256, 256, 0, stream>>>(w1, b1, w1t, bias1);
  build_w2<<<589824 / 256, 256, 0, stream>>>(w2, b2, w2t, bias2);
  // 4) forward FFT
  fft_fwd_w<<<dim3(BB * HH, 3), 256, 0, stream>>>(x, (ushort2*)buf1);
  fft_fwd_h<<<dim3(BB * W2C, 3), 256, 0, stream>>>((const ushort2*)buf1, xf);
  // 5) spectral layer GEMMs (M=16896, N=384, K=384, z = 4 blocks)
  gemm_bt<true, true><<<dim3(132, 3, 4), 256, 0, stream>>>(
      xf, ROWW, 384, w1t, 384, 384 * 384, bias1, 384, buf1, ROWW, 384);
  gemm_bt<false, true><<<dim3(132, 3, 4), 256, 0, stream>>>(
      buf1, ROWW, 384, w2t, 384, 384 * 384, bias2, 384, buf2, ROWW, 384);
  // 6) inverse FFT (+ bias accumulate)
  fft_inv_h<<<dim3(BB * W2C, 3), 256, 0, stream>>>(buf2, (ushort2*)buf1);
  fft_inv_w<<<dim3(BB * HH, 3), 256, 0, stream>>>((const ushort2*)buf1, out);
}